// Round 5
// baseline (180.928 us; speedup 1.0000x reference)
//
#include <hip/hip_runtime.h>
#include <stdint.h>

// ---------------------------------------------------------------------------
// MixingLayer: b=16, m=64, f=128, k=64, L2=16, LMAX=4. ALL I/O IS FP32.
// SEG = [0,1,1,1,2,2,2,2,2,3,3,3,3,3,3,3]
//
// Round-12: barrier-free K-loop (round-11) + sched_barrier(0) fences.
// Round-11 failed with sporadic staleness (absmax 3.47): without s_barrier,
// the backend may hoist step-FF's y-DMA issue above step-(FF-1)'s ds_reads
// of the SAME buffer (rule-18 hazard class); the DMA's LDS write can land
// before the pending ds_read is serviced. Fences (compile-time, zero
// runtime cost) pin: [prev reads] < [YDMA issue] < [vmcnt wait] < [reads].
//   * Block = (kk-slab: 8fx x 32fy = 1024 kk) x (64-col n-half) x (512 m).
//     B slab 64n x 1024kk bf16 = 128 KB DMA'd to LDS ONCE; ONE barrier.
//   * After that: ZERO barriers. Each wave owns 64 m privately; y staged
//     per-step by wave-private global_load_lds (1 KB, 3 bufs, issued 2
//     steps ahead, wave-local counted vmcnt(2) - never 0 in steady state).
//   * x in registers (per 32-m chunk); G (A-fragments) in registers.
//
// ws layout (bytes):
//   Wb2 bf16 [128 slab][131072]  @ 0            (16,777,216)
//   xb  bf16 [1024 m][128 f][16] @ 16777216     ( 4,194,304)
//   ybT bf16 [128 fy][1024 m][16]@ 20971520     ( 4,194,304)
//   Cpart f32 [64][1024][128]    @ 25165824     (33,554,432)
//   wfT f32 [2][64 k][4 l][128f] @ 58720256     (   262,144)
// ---------------------------------------------------------------------------

#define AS1 __attribute__((address_space(1)))
#define AS3 __attribute__((address_space(3)))

typedef __bf16 bf16x8 __attribute__((ext_vector_type(8)));
typedef float f32x4 __attribute__((ext_vector_type(4)));

__device__ __forceinline__ uint16_t f2b(float f) {
  uint32_t u = __float_as_uint(f);
  u += 0x7fffu + ((u >> 16) & 1u);   // RNE
  return (uint16_t)(u >> 16);
}

#if __has_builtin(__builtin_amdgcn_fdot2_f32_bf16)
typedef __bf16 bf16x2 __attribute__((ext_vector_type(2)));
__device__ __forceinline__ float dot2b(uint32_t a, uint32_t b, float c) {
  union { uint32_t u; bf16x2 v; } ua, ub;
  ua.u = a; ub.u = b;
  return __builtin_amdgcn_fdot2_f32_bf16(ua.v, ub.v, c, false);
}
#else
__device__ __forceinline__ float dot2b(uint32_t a, uint32_t b, float c) {
  float a0 = __uint_as_float(a << 16), a1 = __uint_as_float(a & 0xffff0000u);
  float b0 = __uint_as_float(b << 16), b1 = __uint_as_float(b & 0xffff0000u);
  return c + a0 * b0 + a1 * b1;
}
#endif

// ---------------------------------------------------------------------------
// K0: Wb2 (slab-image, swizzle baked) + xb + ybT (transposed) + wfT.
// grid: [0,4096) Wb2 ; [4096,5120) xb ; [5120,6144) ybT ; [6144,6176) wfT.
// ---------------------------------------------------------------------------
__global__ __launch_bounds__(256) void convert_all(
    const float* __restrict__ wx0, const float* __restrict__ wy0,
    const float* __restrict__ x, const float* __restrict__ y,
    const float* __restrict__ wxf, const float* __restrict__ wyf,
    uint16_t* __restrict__ Wb2, uint16_t* __restrict__ xb,
    uint16_t* __restrict__ ybT, float* __restrict__ wfT) {
  int bid = blockIdx.x, tid = threadIdx.x;
  if (bid < 4096) {  // Wb2: unit = 8 consecutive source floats (fx pair x 4 l)
    int c = bid * 256 + tid;               // 0..1048575
    int side = c >= 524288 ? 1 : 0;
    int us = c & 524287;                   // ((k*128 + fy)*64 + fxh)
    int fxh = us & 63;
    int t1 = us >> 6;
    int fy = t1 & 127;
    int k = t1 >> 7;                       // 0..63  (= slab row)
    int fb = fxh >> 2, q = fxh & 3;
    int fyg = fy >> 5, fyl = fy & 31;
    int slab = ((fb << 2) + fyg) * 2 + side;
    int u = ((fyl << 2) + q) ^ (k & 31);   // bank/window swizzle
    size_t dsth = (size_t)slab * 65536 + (size_t)(u >> 3) * 4096 + k * 64 + (u & 7) * 8;
    const float* src = (side ? wy0 : wx0) + (size_t)us * 8;
    float4 v0 = *(const float4*)src;
    float4 v1 = *(const float4*)(src + 4);
    uint32_t o0 = (uint32_t)f2b(v0.x) | ((uint32_t)f2b(v0.y) << 16);
    uint32_t o1 = (uint32_t)f2b(v0.z) | ((uint32_t)f2b(v0.w) << 16);
    uint32_t o2 = (uint32_t)f2b(v1.x) | ((uint32_t)f2b(v1.y) << 16);
    uint32_t o3 = (uint32_t)f2b(v1.z) | ((uint32_t)f2b(v1.w) << 16);
    *(uint4*)(Wb2 + dsth) = make_uint4(o0, o1, o2, o3);
    return;
  }
  if (bid >= 6144) {  // wfT: 32 blocks x 256 thr x 8 elems = 65536
    int base = (bid - 6144) * 2048 + tid * 8;
#pragma unroll
    for (int ii = 0; ii < 8; ++ii) {
      int idx = base + ii;
      int side = idx >> 15, rem = idx & 32767;
      int k = rem >> 9, l = (rem >> 7) & 3, f = rem & 127;
      const float* src = side ? wyf : wxf;
      wfT[idx] = src[((size_t)l * 128 + f) * 64 + k];
    }
    return;
  }
  if (bid < 5120) {  // xb: straight bf16 convert, layout [m][f][16c]
    size_t i = ((size_t)(bid - 4096) * 256 + tid) * 8;
    const float* s = x + i;
    float4 v0 = *(const float4*)s;
    float4 v1 = *(const float4*)(s + 4);
    uint32_t o0 = (uint32_t)f2b(v0.x) | ((uint32_t)f2b(v0.y) << 16);
    uint32_t o1 = (uint32_t)f2b(v0.z) | ((uint32_t)f2b(v0.w) << 16);
    uint32_t o2 = (uint32_t)f2b(v1.x) | ((uint32_t)f2b(v1.y) << 16);
    uint32_t o3 = (uint32_t)f2b(v1.z) | ((uint32_t)f2b(v1.w) << 16);
    *(uint4*)(xb + i) = make_uint4(o0, o1, o2, o3);
    return;
  }
  {  // ybT[fy][m][16c] <- y[m][fy][16c]
    int c = (bid - 5120) * 256 + tid;      // unit = (m*128+fy)*2 + half
    int half = c & 1, fy = (c >> 1) & 127, m = c >> 8;
    const float* s = y + (size_t)c * 8;
    float4 v0 = *(const float4*)s;
    float4 v1 = *(const float4*)(s + 4);
    uint32_t o0 = (uint32_t)f2b(v0.x) | ((uint32_t)f2b(v0.y) << 16);
    uint32_t o1 = (uint32_t)f2b(v0.z) | ((uint32_t)f2b(v0.w) << 16);
    uint32_t o2 = (uint32_t)f2b(v1.x) | ((uint32_t)f2b(v1.y) << 16);
    uint32_t o3 = (uint32_t)f2b(v1.z) | ((uint32_t)f2b(v1.w) << 16);
    *(uint4*)(ybT + ((size_t)fy * 1024 + m) * 16 + half * 8) =
        make_uint4(o0, o1, o2, o3);
  }
}

// ---------------------------------------------------------------------------
// K1: barrier-free fused G-gen + split GEMM (sched_barrier-fenced).
// grid (128, 2), 512 thr. slab = bx: kkg = slab>>1 (fb = kkg>>2, fyg = kkg&3),
// nhalf = slab&1. m0 = by*512; wave w owns m0+w*64..+64 (2 chunks of 32).
// ---------------------------------------------------------------------------
__device__ __forceinline__ void gload_lds16(const void* g, void* l) {
  __builtin_amdgcn_global_load_lds((const AS1 uint32_t*)g, (AS3 uint32_t*)l, 16, 0, 0);
}

#define SB0 __builtin_amdgcn_sched_barrier(0)
#define SFENCE asm volatile("" ::: "memory")
#define VMW(N) asm volatile("s_waitcnt vmcnt(" #N ")" ::: "memory")

#define YDMA(BUF, FF)                                                         \
  gload_lds16(ybT + ((size_t)(fy0 + (FF)) * 1024 + mbase + (lane >> 1)) * 16  \
                  + (lane & 1) * 8,                                           \
              ySw + (BUF) * 512)

#define STEP(CUR, FF, VMN, DOY)                                               \
  do {                                                                        \
    SB0;  /* fence: prev step's reads precede this overwrite-issue */         \
    if (DOY) YDMA(((CUR) + 2) % 3, (FF) + 2);                                 \
    VMW(VMN);                                                                 \
    SB0;  /* fence: reads below may not hoist above the waitcnt */            \
    const uint16_t* yrow = ySw + (CUR) * 512;                                 \
    uint32_t yw[2][8];                                                        \
    _Pragma("unroll") for (int i_ = 0; i_ < 2; ++i_) {                        \
      const uint16_t* bp_ = yrow + (i_ * 16 + r) * 16;                        \
      uint4 a0_ = *(const uint4*)bp_;                                         \
      uint4 a1_ = *(const uint4*)(bp_ + 8);                                   \
      yw[i_][0] = a0_.x; yw[i_][1] = a0_.y; yw[i_][2] = a0_.z; yw[i_][3] = a0_.w; \
      yw[i_][4] = a1_.x; yw[i_][5] = a1_.y; yw[i_][6] = a1_.z; yw[i_][7] = a1_.w; \
    }                                                                         \
    bf16x8 bfr[4];                                                            \
    _Pragma("unroll") for (int j_ = 0; j_ < 4; ++j_) {                        \
      int rowb_ = j_ * 16 + r;                                                \
      int u_ = (((FF) << 2) + q) ^ (rowb_ & 31);                              \
      bfr[j_] = *(const bf16x8*)&sB[(u_ >> 3) * 4096 + rowb_ * 64 + (u_ & 7) * 8]; \
    }                                                                         \
    _Pragma("unroll") for (int i_ = 0; i_ < 2; ++i_) {                        \
      uint32_t yl0 = yw[i_][0] & 0xffffu, yh0 = yw[i_][0] & 0xffff0000u;      \
      uint32_t yl4 = yw[i_][4] & 0xffffu, yh4 = yw[i_][4] & 0xffff0000u;      \
      union { uint32_t u[4]; bf16x8 v; } af;                                  \
      _Pragma("unroll") for (int fxp = 0; fxp < 2; ++fxp) {                   \
        const uint32_t* xp = &xreg[i_][fxp * 8];                              \
        float g0 = dot2b(xp[0], yl0, 0.f);                                    \
        float g1 = dot2b(xp[1], yw[i_][1], dot2b(xp[0], yh0, 0.f));           \
        float g2 = dot2b(xp[4], yl4,                                          \
                    dot2b(xp[3], yw[i_][3], dot2b(xp[2], yw[i_][2], 0.f)));   \
        float g3 = dot2b(xp[7], yw[i_][7], dot2b(xp[6], yw[i_][6],            \
                    dot2b(xp[5], yw[i_][5], dot2b(xp[4], yh4, 0.f))));        \
        af.u[fxp * 2 + 0] = (__float_as_uint(g0) >> 16) |                     \
                            (__float_as_uint(g1) & 0xffff0000u);              \
        af.u[fxp * 2 + 1] = (__float_as_uint(g2) >> 16) |                     \
                            (__float_as_uint(g3) & 0xffff0000u);              \
      }                                                                       \
      _Pragma("unroll") for (int j_ = 0; j_ < 4; ++j_)                        \
        acc[i_][j_] = __builtin_amdgcn_mfma_f32_16x16x32_bf16(af.v, bfr[j_],  \
                                                              acc[i_][j_], 0, 0, 0); \
    }                                                                         \
  } while (0)

__global__ __launch_bounds__(512, 2) void fused_gemm(
    const uint16_t* __restrict__ xb, const uint16_t* __restrict__ ybT,
    const uint16_t* __restrict__ Wb2, float* __restrict__ Cpart) {
  __shared__ __align__(16) uint16_t sB[65536];   // 128 KB B slab (image)
  __shared__ __align__(16) uint16_t yS[12288];   // 8 waves x 3 bufs x 512

  int tid = threadIdx.x, w = tid >> 6, lane = tid & 63;
  int slab = blockIdx.x, kkg = slab >> 1, nhalf = slab & 1;
  int fb = kkg >> 2, fyg = kkg & 3;
  int FB = fb * 8, fy0 = fyg * 32;
  int m0 = blockIdx.y * 512;
  int r = lane & 15, q = lane >> 4;
  uint16_t* ySw = yS + w * 1536;
  int mbase = m0 + w * 64;

  uint32_t xreg[2][16];
  auto loadX = [&]() {
#pragma unroll
    for (int i = 0; i < 2; ++i) {
      const uint16_t* xp0 =
          xb + (size_t)(mbase + i * 16 + r) * 2048 + (FB + 2 * q) * 16;
#pragma unroll
      for (int j2 = 0; j2 < 4; ++j2) {
        uint4 v = *(const uint4*)(xp0 + j2 * 8);
        xreg[i][j2 * 4 + 0] = v.x; xreg[i][j2 * 4 + 1] = v.y;
        xreg[i][j2 * 4 + 2] = v.z; xreg[i][j2 * 4 + 3] = v.w;
      }
    }
  };

  f32x4 acc[2][4];
  f32x4 zero = {0.f, 0.f, 0.f, 0.f};
#pragma unroll
  for (int i = 0; i < 2; ++i)
#pragma unroll
    for (int j = 0; j < 4; ++j) acc[i][j] = zero;

  auto storeC = [&](int mb) {
    float* cb = Cpart + (size_t)kkg * 131072;
#pragma unroll
    for (int i = 0; i < 2; ++i)
#pragma unroll
      for (int j = 0; j < 4; ++j)
#pragma unroll
        for (int reg = 0; reg < 4; ++reg) {
          int mm = mb + i * 16 + q * 4 + reg;
          int nn = nhalf * 64 + j * 16 + r;
          cb[(size_t)mm * 128 + nn] = acc[i][j][reg];
        }
  };

  // ---- prologue: x regs, full B slab DMA, y(0),y(1); ONE barrier.
  loadX();
  SB0; SFENCE;
  const uint16_t* wsrc = Wb2 + (size_t)slab * 65536;
#pragma unroll
  for (int p = 0; p < 16; ++p)
    gload_lds16(wsrc + (size_t)p * 4096 + w * 512 + lane * 8,
                sB + p * 4096 + w * 512);
  SB0; SFENCE;
  YDMA(0, 0);
  YDMA(1, 1);
  SB0;
  VMW(2);                          // drains x + all 16 B rounds; y0,y1 fly
  SB0;
  __builtin_amdgcn_s_barrier();    // the ONLY barrier

  // ---- chunk 0: f = 0..31, free-running, wave-local counted vmcnt.
  for (int ft = 0; ft < 30; ft += 3) {
    STEP(0, ft + 0, 2, true);
    STEP(1, ft + 1, 2, true);
    STEP(2, ft + 2, 2, true);
  }
  STEP(0, 30, 1, false);
  STEP(1, 31, 0, false);

  // ---- inter-chunk: prefetch chunk-1 x/y, then drain chunk-0 acc.
  int m_st0 = mbase;
  mbase += 32;
  SB0;
  loadX();
  SB0; SFENCE;
  YDMA(0, 0);
  YDMA(1, 1);
  SB0; SFENCE;
  storeC(m_st0);
  SB0;
#pragma unroll
  for (int i = 0; i < 2; ++i)
#pragma unroll
    for (int j = 0; j < 4; ++j) acc[i][j] = zero;

  // ---- chunk 1: first two steps wait past the queued stores.
  STEP(0, 0, 10, true);
  STEP(1, 1, 10, true);
  for (int ft = 2; ft < 29; ft += 3) {
    STEP(2, ft + 0, 2, true);
    STEP(0, ft + 1, 2, true);
    STEP(1, ft + 2, 2, true);
  }
  STEP(2, 29, 2, true);
  STEP(0, 30, 1, false);
  STEP(1, 31, 0, false);
  storeC(mbase);
}

// ---------------------------------------------------------------------------
// K2: ONE BLOCK PER bm: inline 64-partial reduce, MLP, gates via wfT, output.
// ---------------------------------------------------------------------------
__global__ __launch_bounds__(256) void finish_kernel(
    const float* __restrict__ x, const float* __restrict__ y,
    const float* __restrict__ wx_mlp, const float* __restrict__ bx_mlp,
    const float* __restrict__ wy_mlp, const float* __restrict__ by_mlp,
    const float* __restrict__ wfT,
    const float* __restrict__ Cpart, float* __restrict__ out) {
  const int seg[16] = {0,1,1,1,2,2,2,2,2,3,3,3,3,3,3,3};
  __shared__ float sred[256];
  __shared__ float sm[128];
  __shared__ float sg[2][128][4];
  int t = threadIdx.x;
  int bm = blockIdx.x;
  int mi = bm & 63;

  {  // inline split-K reduction: sm[n] = sum_{sp<64} Cpart[sp][bm][n]
    int col = t & 127, hh = t >> 7;
    const float* cp = Cpart + (size_t)(hh * 32) * 131072 + (size_t)bm * 128 + col;
    float s = 0.f;
#pragma unroll 8
    for (int sp = 0; sp < 32; ++sp)
      s += cp[(size_t)sp * 131072];
    sred[t] = s;
  }
  __syncthreads();
  if (t < 128) sm[t] = sred[t] + sred[t + 128];  // [0:64)=mx, [64:128)=my
  __syncthreads();

  for (int st = 0; st < 2; ++st) {
    float v = 0.f;
    if (t < 128) {
      int side = t >> 6, j = t & 63;
      const float* wmlp = side ? wy_mlp : wx_mlp;
      const float* bmlp = side ? by_mlp : bx_mlp;
      const float* mv = sm + side * 64;
#pragma unroll 8
      for (int k = 0; k < 64; ++k)
        v += mv[k] * wmlp[(st * 64 + k) * 64 + j];
      v += bmlp[(st * 64 + mi) * 64 + j];
      v = v / (1.f + __expf(-v));
    }
    __syncthreads();
    if (t < 128) sm[t] = v;
    __syncthreads();
  }

  {  // gates: side wave-uniform, coalesced wfT reads
    int side = t >> 7, f = t & 127;
    const float* base = wfT + side * 32768;  // [k][l][f]
    const float* mv = sm + side * 64;
    float gg[4] = {0.f, 0.f, 0.f, 0.f};
#pragma unroll 8
    for (int k = 0; k < 64; ++k) {
      float m2 = mv[k];
#pragma unroll
      for (int l = 0; l < 4; ++l)
        gg[l] += m2 * base[(k * 4 + l) * 128 + f];
    }
#pragma unroll
    for (int l = 0; l < 4; ++l)
      sg[side][f][l] = gg[l] / (1.f + __expf(-gg[l]));
  }
  __syncthreads();

  {  // output: thread -> (f, half), 8 floats; fully coalesced
    int f = t >> 1, half = t & 1;
    size_t base = ((size_t)bm * 128 + f) * 16 + half * 8;
    float4 xa = *(const float4*)(x + base), xb4 = *(const float4*)(x + base + 4);
    float4 ya = *(const float4*)(y + base), yb4 = *(const float4*)(y + base + 4);
    float xv[8] = {xa.x, xa.y, xa.z, xa.w, xb4.x, xb4.y, xb4.z, xb4.w};
    float yv[8] = {ya.x, ya.y, ya.z, ya.w, yb4.x, yb4.y, yb4.z, yb4.w};
    float o[8];
#pragma unroll
    for (int ii = 0; ii < 8; ++ii) {
      int c = half * 8 + ii;
      o[ii] = sg[0][f][seg[c]] * xv[ii] + sg[1][f][seg[c]] * yv[ii];
    }
    *(float4*)(out + base)     = make_float4(o[0], o[1], o[2], o[3]);
    *(float4*)(out + base + 4) = make_float4(o[4], o[5], o[6], o[7]);
  }
}

// ---------------------------------------------------------------------------
extern "C" void kernel_launch(void* const* d_in, const int* in_sizes, int n_in,
                              void* d_out, int out_size, void* d_ws, size_t ws_size,
                              hipStream_t stream) {
  const float* x      = (const float*)d_in[0];
  const float* y      = (const float*)d_in[1];
  const float* wx0    = (const float*)d_in[2];
  const float* wy0    = (const float*)d_in[3];
  const float* wx_mlp = (const float*)d_in[4];
  const float* bx_mlp = (const float*)d_in[5];
  const float* wy_mlp = (const float*)d_in[6];
  const float* by_mlp = (const float*)d_in[7];
  const float* wxf    = (const float*)d_in[8];
  const float* wyf    = (const float*)d_in[9];
  float* out = (float*)d_out;

  uint16_t* Wb2   = (uint16_t*)d_ws;                               // 16,777,216 B
  uint16_t* xb    = (uint16_t*)((char*)d_ws + (size_t)16777216);   //  4,194,304 B
  uint16_t* ybT   = (uint16_t*)((char*)d_ws + (size_t)20971520);   //  4,194,304 B
  float*    Cpart = (float*)((char*)d_ws + (size_t)25165824);      // 33,554,432 B
  float*    wfT   = (float*)((char*)d_ws + (size_t)58720256);      //    262,144 B

  convert_all<<<6176, 256, 0, stream>>>(wx0, wy0, x, y, wxf, wyf, Wb2, xb, ybT, wfT);
  fused_gemm<<<dim3(128, 2), 512, 0, stream>>>(xb, ybT, Wb2, Cpart);
  finish_kernel<<<1024, 256, 0, stream>>>(x, y, wx_mlp, bx_mlp, wy_mlp, by_mlp,
                                          wfT, Cpart, out);
}